// Round 4
// baseline (471.491 us; speedup 1.0000x reference)
//
#include <hip/hip_runtime.h>
#include <hip/hip_bf16.h>

#define S_LEN 2048
#define NH 8
#define HD 64
#define CH 512
#define NEG_INIT (-1.0e30f)
#define MASK_SENT (-30000.0f)

typedef __bf16 bf16;
typedef bf16 bf16x8 __attribute__((ext_vector_type(8)));
typedef bf16 bf16x4 __attribute__((ext_vector_type(4)));
typedef _Float16 f16;
typedef f16 f16x4 __attribute__((ext_vector_type(4)));
typedef float floatx4 __attribute__((ext_vector_type(4)));

// ---------------------------------------------------------------------------
// Mask dtype detection (bool may arrive as int32 / uint8 / float32).
// flag: 0=int32, 1=uint8, 2=float32
// ---------------------------------------------------------------------------
__global__ void detect_mask_kernel(const unsigned char* __restrict__ mb,
                                   int* __restrict__ flag_out) {
    __shared__ int s1, s3;
    if (threadIdx.x == 0) { s1 = 0; s3 = 0; }
    __syncthreads();
    int any1 = 0, any3 = 0;
    int base = threadIdx.x * 16;
    for (int i = base; i < base + 16; ++i) {
        unsigned char bch = mb[i];
        int m = i & 3;
        if (bch != 0) {
            if (m == 1) any1 = 1;
            if (m == 2 || m == 3) any3 = 1;
        }
    }
    if (any1) atomicOr(&s1, 1);
    if (any3) atomicOr(&s3, 1);
    __syncthreads();
    if (threadIdx.x == 0) {
        int f = 0;
        if (s1) f = 1;
        else if (s3) f = 2;
        *flag_out = f;
    }
}

// ---------------------------------------------------------------------------
// Weight prep: W [K][N] fp32 -> WT hi/lo bf16 [N][K]. mats: 0=Wq 1=Wk 2=Wv 3=Wo
// ---------------------------------------------------------------------------
__global__ __launch_bounds__(256) void prep_weights_kernel(
    const float* __restrict__ Wq, const float* __restrict__ Wk,
    const float* __restrict__ Wv, const float* __restrict__ Wo,
    bf16* __restrict__ WThi, bf16* __restrict__ WTlo)
{
    __shared__ float tile[64][65];
    const int t = threadIdx.x;
    const int n0 = blockIdx.x * 64;
    const int k0 = blockIdx.y * 64;
    const int mat = blockIdx.z;
    const float* W = (mat == 0) ? Wq : (mat == 1) ? Wk : (mat == 2) ? Wv : Wo;
    bf16* hi = WThi + (size_t)mat * (CH * CH);
    bf16* lo = WTlo + (size_t)mat * (CH * CH);
#pragma unroll
    for (int i = 0; i < 4; ++i) {
        int row = (t >> 4) + 16 * i;
        int c4 = (t & 15) << 2;
        float4 f = *(const float4*)(W + (size_t)(k0 + row) * CH + n0 + c4);
        tile[row][c4 + 0] = f.x; tile[row][c4 + 1] = f.y;
        tile[row][c4 + 2] = f.z; tile[row][c4 + 3] = f.w;
    }
    __syncthreads();
#pragma unroll
    for (int i = 0; i < 4; ++i) {
        int nr = (t >> 4) + 16 * i;
        int k4 = (t & 15) << 2;
        bf16x4 h, l;
#pragma unroll
        for (int j = 0; j < 4; ++j) {
            float x = tile[k4 + j][nr];
            bf16 hv = (bf16)x;
            h[j] = hv;
            l[j] = (bf16)(x - (float)hv);
        }
        *(bf16x4*)(hi + (size_t)(n0 + nr) * CH + k0 + k4) = h;
        *(bf16x4*)(lo + (size_t)(n0 + nr) * CH + k0 + k4) = l;
    }
}

// ---------------------------------------------------------------------------
// bf16-MFMA GEMM, hi/lo split (fp32-equivalent). BN=64, BM in {64,128}.
// MODE 0: bf16 OUT [b,h,s,d]; MODE 1: bf16 OUT [b,h,d,s] via LDS-transposed
// coalesced epilogue (fixes 16x write amplification); MODE 2: fp32 flat.
// ---------------------------------------------------------------------------
template <int BM, int MODE>
__device__ __forceinline__ void gemm_core(
    bf16* __restrict__ SMEM,
    const float* __restrict__ IN, const bf16* __restrict__ WThi,
    const bf16* __restrict__ WTlo, const float* __restrict__ BI,
    void* __restrict__ OUT, float scale)
{
    constexpr int MI  = BM / 64;       // 16-row strips per wave
    constexpr int TPR = 256 / BM;      // threads per A-row
    constexpr int AF  = 32 / TPR;      // floats per thread per A-stage
    constexpr int F4  = AF / 4;
    constexpr int H8  = AF / 8;
    constexpr int WR  = BM / 4;        // rows per wave

    bf16* As_hi = SMEM;
    bf16* As_lo = SMEM + BM * 40;
    bf16* Bs_hi = SMEM + 2 * BM * 40;
    bf16* Bs_lo = SMEM + 2 * BM * 40 + 64 * 40;

    const int t = threadIdx.x;
    const int w = t >> 6;
    const int m16 = (t & 63) & 15;
    const int quad = (t & 63) >> 4;
    const int m0 = blockIdx.y * BM;
    const int n0 = blockIdx.x * 64;

    const int arow = t / TPR;
    const int akc  = (t % TPR) * AF;
    const int brow = t >> 2;
    const int bkc  = (t & 3) << 3;

    floatx4 acc[MI][4];
#pragma unroll
    for (int mi = 0; mi < MI; ++mi)
#pragma unroll
        for (int ni = 0; ni < 4; ++ni) {
            acc[mi][ni][0] = 0.f; acc[mi][ni][1] = 0.f;
            acc[mi][ni][2] = 0.f; acc[mi][ni][3] = 0.f;
        }

    float4 af[F4];
    bf16x8 pbh, pbl;

    auto loadA = [&](int k0c) {
        const float* p = IN + (size_t)(m0 + arow) * CH + k0c + akc;
#pragma unroll
        for (int i = 0; i < F4; ++i) af[i] = ((const float4*)p)[i];
    };
    auto loadB = [&](int k0c) {
        pbh = *(const bf16x8*)(WThi + (size_t)(n0 + brow) * CH + k0c + bkc);
        pbl = *(const bf16x8*)(WTlo + (size_t)(n0 + brow) * CH + k0c + bkc);
    };
    auto stage = [&]() {
#pragma unroll
        for (int hh = 0; hh < H8; ++hh) {
            bf16x8 h, l;
#pragma unroll
            for (int j = 0; j < 8; ++j) {
                float x = ((const float*)&af[2 * hh])[j];
                bf16 hv = (bf16)x;
                h[j] = hv;
                l[j] = (bf16)(x - (float)hv);
            }
            *(bf16x8*)&As_hi[arow * 40 + akc + 8 * hh] = h;
            *(bf16x8*)&As_lo[arow * 40 + akc + 8 * hh] = l;
        }
        *(bf16x8*)&Bs_hi[brow * 40 + bkc] = pbh;
        *(bf16x8*)&Bs_lo[brow * 40 + bkc] = pbl;
    };

    loadA(0); loadB(0);
    for (int ks = 0; ks < CH / 32; ++ks) {
        __syncthreads();
        stage();
        __syncthreads();
        if (ks + 1 < CH / 32) { loadA(32 * (ks + 1)); loadB(32 * (ks + 1)); }

        bf16x8 bh[4], bl[4];
#pragma unroll
        for (int ni = 0; ni < 4; ++ni) {
            bh[ni] = *(const bf16x8*)&Bs_hi[(16 * ni + m16) * 40 + 8 * quad];
            bl[ni] = *(const bf16x8*)&Bs_lo[(16 * ni + m16) * 40 + 8 * quad];
        }
#pragma unroll
        for (int mi = 0; mi < MI; ++mi) {
            bf16x8 ah = *(const bf16x8*)&As_hi[(WR * w + 16 * mi + m16) * 40 + 8 * quad];
            bf16x8 al = *(const bf16x8*)&As_lo[(WR * w + 16 * mi + m16) * 40 + 8 * quad];
#pragma unroll
            for (int ni = 0; ni < 4; ++ni) {
                acc[mi][ni] = __builtin_amdgcn_mfma_f32_16x16x32_bf16(ah, bh[ni], acc[mi][ni], 0, 0, 0);
                acc[mi][ni] = __builtin_amdgcn_mfma_f32_16x16x32_bf16(ah, bl[ni], acc[mi][ni], 0, 0, 0);
                acc[mi][ni] = __builtin_amdgcn_mfma_f32_16x16x32_bf16(al, bh[ni], acc[mi][ni], 0, 0, 0);
            }
        }
    }

    if (MODE == 1) {
        // transpose tile through LDS -> coalesced [b,h,d,s] bf16 stores
        __syncthreads();
        bf16* T = SMEM;   // 64 x (BM + 8-pad) = 64*136 shorts, fits
#pragma unroll
        for (int mi = 0; mi < MI; ++mi)
#pragma unroll
            for (int r = 0; r < 4; ++r) {
                int rl = WR * w + 16 * mi + 4 * quad + r;
#pragma unroll
                for (int ni = 0; ni < 4; ++ni) {
                    int cl = 16 * ni + m16;
                    T[cl * (BM + 8) + rl] = (bf16)(acc[mi][ni][r] + BI[n0 + cl]);
                }
            }
        __syncthreads();
        int hh = blockIdx.x;                  // n0 = 64*h exactly
        int bb = m0 >> 11;
        int s_base = m0 & (S_LEN - 1);
        int d = t >> 2;
        int s_off = (t & 3) * (BM / 4);
        bf16* po = (bf16*)OUT +
            (((size_t)bb * NH + hh) * HD + d) * S_LEN + s_base + s_off;
#pragma unroll
        for (int j = 0; j < BM / 32; ++j)
            *(bf16x8*)(po + 8 * j) = *(const bf16x8*)&T[d * (BM + 8) + s_off + 8 * j];
    } else {
#pragma unroll
        for (int mi = 0; mi < MI; ++mi)
#pragma unroll
            for (int r = 0; r < 4; ++r) {
                int row = m0 + WR * w + 16 * mi + 4 * quad + r;
                int bb = row >> 11;
                int ss = row & (S_LEN - 1);
#pragma unroll
                for (int ni = 0; ni < 4; ++ni) {
                    int col = n0 + 16 * ni + m16;
                    float v = (acc[mi][ni][r] + BI[col]) * scale;
                    if (MODE == 0) {
                        int hh = col >> 6, dd = col & 63;
                        ((bf16*)OUT)[(((size_t)bb * NH + hh) * S_LEN + ss) * HD + dd] = (bf16)v;
                    } else {
                        ((float*)OUT)[(size_t)row * CH + col] = v;
                    }
                }
            }
    }
}

__global__ __launch_bounds__(256, 2) void qkv_gemm_kernel(
    const float* __restrict__ q_in, const float* __restrict__ k_in,
    const float* __restrict__ v_in,
    const bf16* __restrict__ WThi, const bf16* __restrict__ WTlo,
    const float* __restrict__ bq, const float* __restrict__ bk,
    const float* __restrict__ bv,
    bf16* __restrict__ qp, bf16* __restrict__ kp, bf16* __restrict__ vpT)
{
    __shared__ __attribute__((aligned(16))) bf16 SMEM[2 * 128 * 40 + 2 * 64 * 40];
    int z = blockIdx.z;
    if (z == 0)
        gemm_core<128, 0>(SMEM, q_in, WThi, WTlo, bq, qp, 0.125f);
    else if (z == 1)
        gemm_core<128, 0>(SMEM, k_in, WThi + (size_t)CH * CH,
                          WTlo + (size_t)CH * CH, bk, kp, 1.0f);
    else
        gemm_core<128, 1>(SMEM, v_in, WThi + (size_t)2 * CH * CH,
                          WTlo + (size_t)2 * CH * CH, bv, vpT, 1.0f);
}

__global__ __launch_bounds__(256, 2) void out_gemm_kernel(
    const float* __restrict__ ctx,
    const bf16* __restrict__ WThi, const bf16* __restrict__ WTlo,
    const float* __restrict__ bo, float* __restrict__ out)
{
    __shared__ __attribute__((aligned(16))) bf16 SMEM[2 * 64 * 40 + 2 * 64 * 40];
    gemm_core<64, 2>(SMEM, ctx, WThi + (size_t)3 * CH * CH,
                     WTlo + (size_t)3 * CH * CH, bo, out, 1.0f);
}

// ---------------------------------------------------------------------------
// Flash attention, split-K (2 chunks of 1024 keys) + XCD swizzle.
// 1024 blocks; flat id fid: xcd = fid&7; all 32 q-blocks of one (b,h,c)
// group share fid%8 -> same XCD -> K/V (0.5 MB bf16) L2-resident.
// LDS 36.9KB -> 4 blocks/CU. Partial O (unnormalized) + (m,l) to ws; merged
// by merge_kernel.
// ---------------------------------------------------------------------------
__global__ __launch_bounds__(256, 4) void attn_kernel(
    const bf16* __restrict__ qp, const bf16* __restrict__ kp,
    const bf16* __restrict__ vpT, const float* __restrict__ bias,
    const void* __restrict__ mask, const int* __restrict__ flagp,
    float* __restrict__ O0, float* __restrict__ O1,
    float2* __restrict__ ml)
{
    __shared__ __attribute__((aligned(16))) bf16 Kbf[64 * 72];
    __shared__ __attribute__((aligned(16))) bf16 VsT[64 * 72];
    __shared__ __attribute__((aligned(16))) bf16 Pbf[64 * 72];
    __shared__ __attribute__((aligned(16))) f16  sb16[64 * 72];

    const int t    = threadIdx.x;
    const int w    = t >> 6;
    const int lane = t & 63;
    const int m    = lane & 15;
    const int quad = lane >> 4;

    // XCD-aware swizzle: fid%8 constant within a (b,h,c) group
    const int fid   = blockIdx.x + 32 * (blockIdx.y + 8 * blockIdx.z);
    const int xcd   = fid & 7;
    const int rest  = fid >> 3;
    const int q_idx = rest & 31;
    const int g     = xcd | ((rest >> 5) << 3);   // 0..31
    const int h     = g & 7;
    const int bc    = g >> 3;
    const int b     = bc >> 1;
    const int c     = bc & 1;

    const int q0 = q_idx * 64;
    const int bh = b * NH + h;
    const int kbase = c * (S_LEN / 2);
    const int flag = *flagp;

    // Q fragments (bf16, prescaled 1/8)
    bf16x8 qf[2];
    {
        const bf16* qrow = qp + ((size_t)bh * S_LEN + q0 + 16 * w + m) * HD + 8 * quad;
        qf[0] = *(const bf16x8*)(qrow);
        qf[1] = *(const bf16x8*)(qrow + 32);
    }

    floatx4 ctx[4];
    float mrow[4], lrow[4];
#pragma unroll
    for (int tt = 0; tt < 4; ++tt) { ctx[tt][0]=0.f; ctx[tt][1]=0.f; ctx[tt][2]=0.f; ctx[tt][3]=0.f; }
#pragma unroll
    for (int r = 0; r < 4; ++r) { mrow[r] = NEG_INIT; lrow[r] = 0.f; }

    bf16x8 kreg[2], vreg[2];
    float4 breg[4];
    uint4  mreg[4];

    auto prefetch = [&](int k0) {
#pragma unroll
        for (int i = 0; i < 2; ++i) {
            int fl = t + 256 * i;
            int row = fl >> 3;
            int c8 = (fl & 7) << 3;
            kreg[i] = *(const bf16x8*)(kp  + ((size_t)bh * S_LEN + k0 + row) * HD + c8);
            vreg[i] = *(const bf16x8*)(vpT + ((size_t)bh * HD + row) * S_LEN + k0 + c8);
        }
#pragma unroll
        for (int i = 0; i < 4; ++i) {
            int fl = t + 256 * i;
            int row = fl >> 4;
            int c4 = (fl & 15) << 2;
            int grow = q0 + row;
            breg[i] = *(const float4*)(bias + ((size_t)h * S_LEN + grow) * S_LEN + k0 + c4);
            size_t mi0 = (size_t)grow * S_LEN + k0 + c4;
            if (flag == 1)
                mreg[i].x = *(const unsigned int*)((const unsigned char*)mask + mi0);
            else
                mreg[i] = *(const uint4*)((const unsigned int*)mask + mi0);
        }
    };
    auto stage = [&]() {
#pragma unroll
        for (int i = 0; i < 2; ++i) {
            int fl = t + 256 * i;
            int row = fl >> 3;
            int c8 = (fl & 7) << 3;
            *(bf16x8*)&Kbf[row * 72 + c8] = kreg[i];
            *(bf16x8*)&VsT[row * 72 + c8] = vreg[i];
        }
#pragma unroll
        for (int i = 0; i < 4; ++i) {
            int fl = t + 256 * i;
            int row = fl >> 4;
            int c4 = (fl & 15) << 2;
            float4 bf = breg[i];
            unsigned mj0, mj1, mj2, mj3;
            if (flag == 1) {
                unsigned mx = mreg[i].x;
                mj0 = mx & 255u; mj1 = (mx >> 8) & 255u;
                mj2 = (mx >> 16) & 255u; mj3 = mx >> 24;
            } else {
                mj0 = mreg[i].x; mj1 = mreg[i].y; mj2 = mreg[i].z; mj3 = mreg[i].w;
            }
            f16x4 sb;
            sb[0] = (f16)(mj0 ? bf.x : MASK_SENT);
            sb[1] = (f16)(mj1 ? bf.y : MASK_SENT);
            sb[2] = (f16)(mj2 ? bf.z : MASK_SENT);
            sb[3] = (f16)(mj3 ? bf.w : MASK_SENT);
            *(f16x4*)&sb16[row * 72 + c4] = sb;
        }
    };

    prefetch(kbase);
    for (int k0 = kbase; k0 < kbase + S_LEN / 2; k0 += 64) {
        __syncthreads();
        stage();
        __syncthreads();
        if (k0 + 64 < kbase + S_LEN / 2) prefetch(k0 + 64);

        floatx4 sc[4];
#pragma unroll
        for (int tt = 0; tt < 4; ++tt) { sc[tt][0]=0.f; sc[tt][1]=0.f; sc[tt][2]=0.f; sc[tt][3]=0.f; }
#pragma unroll
        for (int st = 0; st < 2; ++st)
#pragma unroll
            for (int tt = 0; tt < 4; ++tt) {
                bf16x8 kf = *(const bf16x8*)&Kbf[(16 * tt + m) * 72 + 8 * quad + 32 * st];
                sc[tt] = __builtin_amdgcn_mfma_f32_16x16x32_bf16(qf[st], kf, sc[tt], 0, 0, 0);
            }

        float alpha[4];
#pragma unroll
        for (int r = 0; r < 4; ++r) {
            int lrowq = 16 * w + 4 * quad + r;
            float s[4];
#pragma unroll
            for (int tt = 0; tt < 4; ++tt)
                s[tt] = sc[tt][r] + (float)sb16[lrowq * 72 + 16 * tt + m];
            float mx = fmaxf(fmaxf(s[0], s[1]), fmaxf(s[2], s[3]));
            mx = fmaxf(mx, __shfl_xor(mx, 1));
            mx = fmaxf(mx, __shfl_xor(mx, 2));
            mx = fmaxf(mx, __shfl_xor(mx, 4));
            mx = fmaxf(mx, __shfl_xor(mx, 8));
            float mnew = fmaxf(mrow[r], mx);
            float al = __expf(mrow[r] - mnew);
            float ls = 0.f;
#pragma unroll
            for (int tt = 0; tt < 4; ++tt) {
                float p = (s[tt] <= -20000.f) ? 0.f : __expf(s[tt] - mnew);
                ls += p;
                Pbf[lrowq * 72 + 16 * tt + m] = (bf16)p;
            }
            ls += __shfl_xor(ls, 1);
            ls += __shfl_xor(ls, 2);
            ls += __shfl_xor(ls, 4);
            ls += __shfl_xor(ls, 8);
            lrow[r] = lrow[r] * al + ls;
            mrow[r] = mnew;
            alpha[r] = al;
        }
#pragma unroll
        for (int tt = 0; tt < 4; ++tt)
#pragma unroll
            for (int r = 0; r < 4; ++r) ctx[tt][r] *= alpha[r];

#pragma unroll
        for (int st = 0; st < 2; ++st) {
            bf16x8 pf = *(const bf16x8*)&Pbf[(16 * w + m) * 72 + 8 * quad + 32 * st];
#pragma unroll
            for (int tt = 0; tt < 4; ++tt) {
                bf16x8 vf = *(const bf16x8*)&VsT[(16 * tt + m) * 72 + 8 * quad + 32 * st];
                ctx[tt] = __builtin_amdgcn_mfma_f32_16x16x32_bf16(pf, vf, ctx[tt], 0, 0, 0);
            }
        }
    }

    // epilogue: unnormalized partial O + (m,l)
    float* Op = (c == 0) ? O0 : O1;
#pragma unroll
    for (int r = 0; r < 4; ++r) {
        int grow = q0 + 16 * w + 4 * quad + r;
#pragma unroll
        for (int tt = 0; tt < 4; ++tt)
            Op[((size_t)b * S_LEN + grow) * CH + h * HD + 16 * tt + m] = ctx[tt][r];
        if (m == 0) {
            float2 v; v.x = mrow[r]; v.y = lrow[r];
            ml[(((size_t)c * 2 + b) * NH + h) * S_LEN + grow] = v;
        }
    }
}

// Combine the two split-K partials; writes ctx in-place over O0.
__global__ __launch_bounds__(256) void merge_kernel(
    float* __restrict__ O0, const float* __restrict__ O1,
    const float2* __restrict__ ml)
{
    int idx = blockIdx.x * 256 + threadIdx.x;    // 524288 threads x float4
    int i4 = idx << 2;
    int col = i4 & (CH - 1);
    int h = col >> 6;
    int srow = (i4 >> 9) & (S_LEN - 1);
    int b = i4 >> 20;
    float2 a = ml[(((size_t)0 + b) * NH + h) * S_LEN + srow];
    float2 d = ml[(((size_t)2 + b) * NH + h) * S_LEN + srow];
    float ms = fmaxf(a.x, d.x);
    float w0 = __expf(a.x - ms), w1 = __expf(d.x - ms);
    float den = a.y * w0 + d.y * w1;
    float inv = den > 0.f ? 1.f / den : 0.f;
    float4 o0 = ((const float4*)O0)[idx];
    float4 o1 = ((const float4*)O1)[idx];
    float4 r;
    r.x = (o0.x * w0 + o1.x * w1) * inv;
    r.y = (o0.y * w0 + o1.y * w1) * inv;
    r.z = (o0.z * w0 + o1.z * w1) * inv;
    r.w = (o0.w * w0 + o1.w * w1) * inv;
    ((float4*)O0)[idx] = r;
}

extern "C" void kernel_launch(void* const* d_in, const int* in_sizes, int n_in,
                              void* d_out, int out_size, void* d_ws, size_t ws_size,
                              hipStream_t stream) {
    const float* k_in = (const float*)d_in[0];
    const float* v_in = (const float*)d_in[1];
    const float* q_in = (const float*)d_in[2];
    const void*  mask = d_in[3];
    const float* bias = (const float*)d_in[4];
    const float* Wq = (const float*)d_in[5];
    const float* bq = (const float*)d_in[6];
    const float* Wk = (const float*)d_in[7];
    const float* bk = (const float*)d_in[8];
    const float* Wv = (const float*)d_in[9];
    const float* bv = (const float*)d_in[10];
    const float* Wo = (const float*)d_in[11];
    const float* bo = (const float*)d_in[12];
    float* out = (float*)d_out;

    float* wsf = (float*)d_ws;
    bf16*  qp   = (bf16*)wsf;                     // [B,H,S,D] bf16  4 MB
    bf16*  kp   = (bf16*)(wsf + 1048576);         // 4 MB
    bf16*  vpT  = (bf16*)(wsf + 2097152);         // [B,H,D,S] bf16  4 MB
    float* ctx  = wsf + 3145728;                  // O0 / merged ctx 8 MB
    float* O1   = wsf + 5242880;                  // 8 MB
    bf16*  WThi = (bf16*)(wsf + 7340032);         // 2 MB
    bf16*  WTlo = (bf16*)(wsf + 7864320);         // 2 MB
    float2* ml  = (float2*)(wsf + 8388608);       // 512 KB
    int*   flag = (int*)(wsf + 8519680);

    detect_mask_kernel<<<1, 256, 0, stream>>>((const unsigned char*)mask, flag);
    prep_weights_kernel<<<dim3(8, 8, 4), 256, 0, stream>>>(
        Wq, Wk, Wv, Wo, WThi, WTlo);
    qkv_gemm_kernel<<<dim3(8, 32, 3), 256, 0, stream>>>(
        q_in, k_in, v_in, WThi, WTlo, bq, bk, bv, qp, kp, vpT);
    attn_kernel<<<dim3(32, 8, 4), 256, 0, stream>>>(
        qp, kp, vpT, bias, mask, flag, ctx, O1, ml);
    merge_kernel<<<2048, 256, 0, stream>>>(ctx, O1, ml);
    out_gemm_kernel<<<dim3(8, 64), 256, 0, stream>>>(
        ctx, WThi, WTlo, bo, out);
}

// Round 5
// 393.268 us; speedup vs baseline: 1.1989x; 1.1989x over previous
//
#include <hip/hip_runtime.h>
#include <hip/hip_bf16.h>

#define S_LEN 2048
#define NH 8
#define HD 64
#define CH 512
#define NEG_INIT (-1.0e30f)
#define MASK_SENT (-30000.0f)

typedef __bf16 bf16;
typedef bf16 bf16x8 __attribute__((ext_vector_type(8)));
typedef bf16 bf16x4 __attribute__((ext_vector_type(4)));
typedef _Float16 f16;
typedef f16 f16x4 __attribute__((ext_vector_type(4)));
typedef f16 f16x8 __attribute__((ext_vector_type(8)));
typedef float floatx4 __attribute__((ext_vector_type(4)));

// ---------------------------------------------------------------------------
// Mask dtype detection (bool may arrive as int32 / uint8 / float32).
// flag: 0=int32, 1=uint8, 2=float32
// ---------------------------------------------------------------------------
__global__ void detect_mask_kernel(const unsigned char* __restrict__ mb,
                                   int* __restrict__ flag_out) {
    __shared__ int s1, s3;
    if (threadIdx.x == 0) { s1 = 0; s3 = 0; }
    __syncthreads();
    int any1 = 0, any3 = 0;
    int base = threadIdx.x * 16;
    for (int i = base; i < base + 16; ++i) {
        unsigned char bch = mb[i];
        int m = i & 3;
        if (bch != 0) {
            if (m == 1) any1 = 1;
            if (m == 2 || m == 3) any3 = 1;
        }
    }
    if (any1) atomicOr(&s1, 1);
    if (any3) atomicOr(&s3, 1);
    __syncthreads();
    if (threadIdx.x == 0) {
        int f = 0;
        if (s1) f = 1;
        else if (s3) f = 2;
        *flag_out = f;
    }
}

// ---------------------------------------------------------------------------
// Weight prep: W [K][N] fp32 -> WT hi/lo bf16 [N][K]. mats: 0=Wq 1=Wk 2=Wv 3=Wo
// ---------------------------------------------------------------------------
__global__ __launch_bounds__(256) void prep_weights_kernel(
    const float* __restrict__ Wq, const float* __restrict__ Wk,
    const float* __restrict__ Wv, const float* __restrict__ Wo,
    bf16* __restrict__ WThi, bf16* __restrict__ WTlo)
{
    __shared__ float tile[64][65];
    const int t = threadIdx.x;
    const int n0 = blockIdx.x * 64;
    const int k0 = blockIdx.y * 64;
    const int mat = blockIdx.z;
    const float* W = (mat == 0) ? Wq : (mat == 1) ? Wk : (mat == 2) ? Wv : Wo;
    bf16* hi = WThi + (size_t)mat * (CH * CH);
    bf16* lo = WTlo + (size_t)mat * (CH * CH);
#pragma unroll
    for (int i = 0; i < 4; ++i) {
        int row = (t >> 4) + 16 * i;
        int c4 = (t & 15) << 2;
        float4 f = *(const float4*)(W + (size_t)(k0 + row) * CH + n0 + c4);
        tile[row][c4 + 0] = f.x; tile[row][c4 + 1] = f.y;
        tile[row][c4 + 2] = f.z; tile[row][c4 + 3] = f.w;
    }
    __syncthreads();
#pragma unroll
    for (int i = 0; i < 4; ++i) {
        int nr = (t >> 4) + 16 * i;
        int k4 = (t & 15) << 2;
        bf16x4 h, l;
#pragma unroll
        for (int j = 0; j < 4; ++j) {
            float x = tile[k4 + j][nr];
            bf16 hv = (bf16)x;
            h[j] = hv;
            l[j] = (bf16)(x - (float)hv);
        }
        *(bf16x4*)(hi + (size_t)(n0 + nr) * CH + k0 + k4) = h;
        *(bf16x4*)(lo + (size_t)(n0 + nr) * CH + k0 + k4) = l;
    }
}

// ---------------------------------------------------------------------------
// sbias prep: sbias[h,q,k] = mask[q,k] ? (f16)bias[h,q,k] : -30000.
// Folds mask into bias once -> attn reads ONE f16 stream (halves demand,
// removes per-iter mask logic). 1M threads x 4 k-elems x 8 heads.
// ---------------------------------------------------------------------------
__global__ __launch_bounds__(256) void prep_sbias_kernel(
    const float* __restrict__ bias, const void* __restrict__ mask,
    const int* __restrict__ flagp, f16* __restrict__ sbias)
{
    int idx = blockIdx.x * 256 + threadIdx.x;   // S*S/4 = 1M threads
    int i4 = idx << 2;
    int q = i4 >> 11;
    int k = i4 & (S_LEN - 1);
    int flag = *flagp;
    unsigned mj[4];
    if (flag == 1) {
        unsigned mx = *(const unsigned*)((const unsigned char*)mask + (size_t)q * S_LEN + k);
        mj[0] = mx & 255u; mj[1] = (mx >> 8) & 255u;
        mj[2] = (mx >> 16) & 255u; mj[3] = mx >> 24;
    } else {
        uint4 mx = *(const uint4*)((const unsigned*)mask + (size_t)q * S_LEN + k);
        mj[0] = mx.x; mj[1] = mx.y; mj[2] = mx.z; mj[3] = mx.w;
    }
#pragma unroll
    for (int h = 0; h < NH; ++h) {
        float4 bv = *(const float4*)(bias + ((size_t)h * S_LEN + q) * S_LEN + k);
        f16x4 sb;
        sb[0] = (f16)(mj[0] ? bv.x : MASK_SENT);
        sb[1] = (f16)(mj[1] ? bv.y : MASK_SENT);
        sb[2] = (f16)(mj[2] ? bv.z : MASK_SENT);
        sb[3] = (f16)(mj[3] ? bv.w : MASK_SENT);
        *(f16x4*)(sbias + ((size_t)h * S_LEN + q) * S_LEN + k) = sb;
    }
}

// ---------------------------------------------------------------------------
// bf16-MFMA GEMM, hi/lo split (fp32-equivalent). BM=BN=128, BK=32, 256 thr.
// ASPLIT: A already split into hi/lo bf16 (pure-copy staging).
// MODE 0: bf16 OUT [b,h,s,d]; MODE 1: bf16 OUT [b,h,d,s] (LDS-transposed
// coalesced epilogue); MODE 2: fp32 flat [row,col].
// ---------------------------------------------------------------------------
template <int MODE, bool ASPLIT>
__device__ __forceinline__ void gemm_core(
    bf16* __restrict__ SMEM,
    const float* __restrict__ INF,
    const bf16* __restrict__ INH, const bf16* __restrict__ INL,
    const bf16* __restrict__ WThi, const bf16* __restrict__ WTlo,
    const float* __restrict__ BI, void* __restrict__ OUT, float scale)
{
    bf16* As_hi = SMEM;                 // 128 x 40
    bf16* As_lo = SMEM + 128 * 40;
    bf16* Bs_hi = SMEM + 2 * 128 * 40;
    bf16* Bs_lo = SMEM + 3 * 128 * 40;

    const int t = threadIdx.x;
    const int w = t >> 6;
    const int m16 = (t & 63) & 15;
    const int quad = (t & 63) >> 4;
    const int m0 = blockIdx.y * 128;
    const int n0 = blockIdx.x * 128;

    const int arow = t >> 1;            // 0..127
    const int akc  = (t & 1) << 4;      // 0 or 16

    floatx4 acc[2][8];
#pragma unroll
    for (int mi = 0; mi < 2; ++mi)
#pragma unroll
        for (int ni = 0; ni < 8; ++ni) {
            acc[mi][ni][0] = 0.f; acc[mi][ni][1] = 0.f;
            acc[mi][ni][2] = 0.f; acc[mi][ni][3] = 0.f;
        }

    float4 af[4];
    bf16x8 pah[2], pal[2], pbh[2], pbl[2];

    auto loadA = [&](int k0c) {
        if (ASPLIT) {
            const bf16* ph = INH + (size_t)(m0 + arow) * CH + k0c + akc;
            const bf16* pl = INL + (size_t)(m0 + arow) * CH + k0c + akc;
            pah[0] = ((const bf16x8*)ph)[0]; pah[1] = ((const bf16x8*)ph)[1];
            pal[0] = ((const bf16x8*)pl)[0]; pal[1] = ((const bf16x8*)pl)[1];
        } else {
            const float* p = INF + (size_t)(m0 + arow) * CH + k0c + akc;
#pragma unroll
            for (int i = 0; i < 4; ++i) af[i] = ((const float4*)p)[i];
        }
    };
    auto loadB = [&](int k0c) {
        const bf16* ph = WThi + (size_t)(n0 + arow) * CH + k0c + akc;
        const bf16* pl = WTlo + (size_t)(n0 + arow) * CH + k0c + akc;
        pbh[0] = ((const bf16x8*)ph)[0]; pbh[1] = ((const bf16x8*)ph)[1];
        pbl[0] = ((const bf16x8*)pl)[0]; pbl[1] = ((const bf16x8*)pl)[1];
    };
    auto stage = [&]() {
        if (ASPLIT) {
            *(bf16x8*)&As_hi[arow * 40 + akc + 0] = pah[0];
            *(bf16x8*)&As_hi[arow * 40 + akc + 8] = pah[1];
            *(bf16x8*)&As_lo[arow * 40 + akc + 0] = pal[0];
            *(bf16x8*)&As_lo[arow * 40 + akc + 8] = pal[1];
        } else {
#pragma unroll
            for (int hh = 0; hh < 2; ++hh) {
                bf16x8 h, l;
#pragma unroll
                for (int j = 0; j < 8; ++j) {
                    float x = ((const float*)&af[2 * hh])[j];
                    bf16 hv = (bf16)x;
                    h[j] = hv;
                    l[j] = (bf16)(x - (float)hv);
                }
                *(bf16x8*)&As_hi[arow * 40 + akc + 8 * hh] = h;
                *(bf16x8*)&As_lo[arow * 40 + akc + 8 * hh] = l;
            }
        }
        *(bf16x8*)&Bs_hi[arow * 40 + akc + 0] = pbh[0];
        *(bf16x8*)&Bs_hi[arow * 40 + akc + 8] = pbh[1];
        *(bf16x8*)&Bs_lo[arow * 40 + akc + 0] = pbl[0];
        *(bf16x8*)&Bs_lo[arow * 40 + akc + 8] = pbl[1];
    };

    loadA(0); loadB(0);
    for (int ks = 0; ks < CH / 32; ++ks) {
        __syncthreads();
        stage();
        __syncthreads();
        if (ks + 1 < CH / 32) { loadA(32 * (ks + 1)); loadB(32 * (ks + 1)); }

        bf16x8 ah[2], al[2];
#pragma unroll
        for (int mi = 0; mi < 2; ++mi) {
            ah[mi] = *(const bf16x8*)&As_hi[(32 * w + 16 * mi + m16) * 40 + 8 * quad];
            al[mi] = *(const bf16x8*)&As_lo[(32 * w + 16 * mi + m16) * 40 + 8 * quad];
        }
#pragma unroll
        for (int ni = 0; ni < 8; ++ni) {
            bf16x8 bh = *(const bf16x8*)&Bs_hi[(16 * ni + m16) * 40 + 8 * quad];
            bf16x8 bl = *(const bf16x8*)&Bs_lo[(16 * ni + m16) * 40 + 8 * quad];
#pragma unroll
            for (int mi = 0; mi < 2; ++mi) {
                acc[mi][ni] = __builtin_amdgcn_mfma_f32_16x16x32_bf16(ah[mi], bh, acc[mi][ni], 0, 0, 0);
                acc[mi][ni] = __builtin_amdgcn_mfma_f32_16x16x32_bf16(ah[mi], bl, acc[mi][ni], 0, 0, 0);
                acc[mi][ni] = __builtin_amdgcn_mfma_f32_16x16x32_bf16(al[mi], bh, acc[mi][ni], 0, 0, 0);
            }
        }
    }

    if (MODE == 1) {
        // transpose through LDS -> coalesced [b,h,d,s] bf16 stores
        __syncthreads();
        bf16* T = SMEM;    // 128 cols x 136 = 34.8 KB, fits in 40 KB
#pragma unroll
        for (int mi = 0; mi < 2; ++mi)
#pragma unroll
            for (int r = 0; r < 4; ++r) {
                int rl = 32 * w + 16 * mi + 4 * quad + r;
#pragma unroll
                for (int ni = 0; ni < 8; ++ni) {
                    int cl = 16 * ni + m16;
                    T[cl * 136 + rl] = (bf16)(acc[mi][ni][r] + BI[n0 + cl]);
                }
            }
        __syncthreads();
        int bb = m0 >> 11;
        int s_base = m0 & (S_LEN - 1);
        int cl = t >> 1;                 // 0..127
        int s_off = (t & 1) * 64;
        int gc = n0 + cl;
        int hh = gc >> 6, dd = gc & 63;
        bf16* po = (bf16*)OUT +
            (((size_t)bb * NH + hh) * HD + dd) * S_LEN + s_base + s_off;
#pragma unroll
        for (int j = 0; j < 8; ++j)
            *(bf16x8*)(po + 8 * j) = *(const bf16x8*)&T[cl * 136 + s_off + 8 * j];
    } else {
#pragma unroll
        for (int mi = 0; mi < 2; ++mi)
#pragma unroll
            for (int r = 0; r < 4; ++r) {
                int row = m0 + 32 * w + 16 * mi + 4 * quad + r;
                int bb = row >> 11;
                int ss = row & (S_LEN - 1);
#pragma unroll
                for (int ni = 0; ni < 8; ++ni) {
                    int col = n0 + 16 * ni + m16;
                    float v = (acc[mi][ni][r] + BI[col]) * scale;
                    if (MODE == 0) {
                        int hh = col >> 6, dd = col & 63;
                        ((bf16*)OUT)[(((size_t)bb * NH + hh) * S_LEN + ss) * HD + dd] = (bf16)v;
                    } else {
                        ((float*)OUT)[(size_t)row * CH + col] = v;
                    }
                }
            }
    }
}

__global__ __launch_bounds__(256, 2) void qkv_gemm_kernel(
    const float* __restrict__ q_in, const float* __restrict__ k_in,
    const float* __restrict__ v_in,
    const bf16* __restrict__ WThi, const bf16* __restrict__ WTlo,
    const float* __restrict__ bq, const float* __restrict__ bk,
    const float* __restrict__ bv,
    bf16* __restrict__ qp, bf16* __restrict__ kp, bf16* __restrict__ vpT)
{
    __shared__ __attribute__((aligned(16))) bf16 SMEM[4 * 128 * 40];
    int z = blockIdx.z;
    if (z == 0)
        gemm_core<0, false>(SMEM, q_in, nullptr, nullptr, WThi, WTlo, bq, qp, 0.125f);
    else if (z == 1)
        gemm_core<0, false>(SMEM, k_in, nullptr, nullptr,
                            WThi + (size_t)CH * CH, WTlo + (size_t)CH * CH, bk, kp, 1.0f);
    else
        gemm_core<1, false>(SMEM, v_in, nullptr, nullptr,
                            WThi + (size_t)2 * CH * CH, WTlo + (size_t)2 * CH * CH, bv, vpT, 1.0f);
}

__global__ __launch_bounds__(256, 2) void out_gemm_kernel(
    const bf16* __restrict__ ctxhi, const bf16* __restrict__ ctxlo,
    const bf16* __restrict__ WThi, const bf16* __restrict__ WTlo,
    const float* __restrict__ bo, float* __restrict__ out)
{
    __shared__ __attribute__((aligned(16))) bf16 SMEM[4 * 128 * 40];
    gemm_core<2, true>(SMEM, nullptr, ctxhi, ctxlo,
                       WThi + (size_t)3 * CH * CH, WTlo + (size_t)3 * CH * CH, bo, out, 1.0f);
}

// ---------------------------------------------------------------------------
// Flash attention (round-3 structure: single pass, linear block order,
// 512 co-resident blocks) with precomputed sbias f16 stream.
// LDS 36.9 KB -> 4 blocks/CU. Per-iter prefetch: 6 vector loads (K,V,sbias).
// Epilogue writes ctx pre-split hi/lo bf16 for the out-GEMM.
// ---------------------------------------------------------------------------
__global__ __launch_bounds__(256, 4) void attn_kernel(
    const bf16* __restrict__ qp, const bf16* __restrict__ kp,
    const bf16* __restrict__ vpT, const f16* __restrict__ sbias,
    bf16* __restrict__ ctxhi, bf16* __restrict__ ctxlo)
{
    __shared__ __attribute__((aligned(16))) bf16 Kbf[64 * 72];
    __shared__ __attribute__((aligned(16))) bf16 VsT[64 * 72];
    __shared__ __attribute__((aligned(16))) bf16 Pbf[64 * 72];
    __shared__ __attribute__((aligned(16))) f16  sb16[64 * 72];

    const int t    = threadIdx.x;
    const int w    = t >> 6;
    const int lane = t & 63;
    const int m    = lane & 15;
    const int quad = lane >> 4;
    const int q0   = blockIdx.x * 64;
    const int h    = blockIdx.y;
    const int b    = blockIdx.z;
    const int bh   = b * NH + h;

    // Q fragments (bf16, prescaled 1/8)
    bf16x8 qf[2];
    {
        const bf16* qrow = qp + ((size_t)bh * S_LEN + q0 + 16 * w + m) * HD + 8 * quad;
        qf[0] = *(const bf16x8*)(qrow);
        qf[1] = *(const bf16x8*)(qrow + 32);
    }

    floatx4 ctx[4];
    float mrow[4], lrow[4];
#pragma unroll
    for (int tt = 0; tt < 4; ++tt) { ctx[tt][0]=0.f; ctx[tt][1]=0.f; ctx[tt][2]=0.f; ctx[tt][3]=0.f; }
#pragma unroll
    for (int r = 0; r < 4; ++r) { mrow[r] = NEG_INIT; lrow[r] = 0.f; }

    bf16x8 kreg[2], vreg[2];
    f16x8  sreg[2];

    auto prefetch = [&](int k0) {
#pragma unroll
        for (int i = 0; i < 2; ++i) {
            int fl = t + 256 * i;
            int row = fl >> 3;
            int c8 = (fl & 7) << 3;
            kreg[i] = *(const bf16x8*)(kp  + ((size_t)bh * S_LEN + k0 + row) * HD + c8);
            vreg[i] = *(const bf16x8*)(vpT + ((size_t)bh * HD + row) * S_LEN + k0 + c8);
            sreg[i] = *(const f16x8*)(sbias + ((size_t)h * S_LEN + q0 + row) * S_LEN + k0 + c8);
        }
    };
    auto stage = [&]() {
#pragma unroll
        for (int i = 0; i < 2; ++i) {
            int fl = t + 256 * i;
            int row = fl >> 3;
            int c8 = (fl & 7) << 3;
            *(bf16x8*)&Kbf[row * 72 + c8] = kreg[i];
            *(bf16x8*)&VsT[row * 72 + c8] = vreg[i];
            *(f16x8*)&sb16[row * 72 + c8] = sreg[i];
        }
    };

    prefetch(0);
    for (int k0 = 0; k0 < S_LEN; k0 += 64) {
        __syncthreads();    // prev iter's LDS reads done before restage
        stage();
        __syncthreads();
        if (k0 + 64 < S_LEN) prefetch(k0 + 64);   // hide next tile's latency

        floatx4 sc[4];
#pragma unroll
        for (int tt = 0; tt < 4; ++tt) { sc[tt][0]=0.f; sc[tt][1]=0.f; sc[tt][2]=0.f; sc[tt][3]=0.f; }
#pragma unroll
        for (int st = 0; st < 2; ++st)
#pragma unroll
            for (int tt = 0; tt < 4; ++tt) {
                bf16x8 kf = *(const bf16x8*)&Kbf[(16 * tt + m) * 72 + 8 * quad + 32 * st];
                sc[tt] = __builtin_amdgcn_mfma_f32_16x16x32_bf16(qf[st], kf, sc[tt], 0, 0, 0);
            }

        float alpha[4];
#pragma unroll
        for (int r = 0; r < 4; ++r) {
            int lrowq = 16 * w + 4 * quad + r;
            float s[4];
#pragma unroll
            for (int tt = 0; tt < 4; ++tt)
                s[tt] = sc[tt][r] + (float)sb16[lrowq * 72 + 16 * tt + m];
            float mx = fmaxf(fmaxf(s[0], s[1]), fmaxf(s[2], s[3]));
            mx = fmaxf(mx, __shfl_xor(mx, 1));
            mx = fmaxf(mx, __shfl_xor(mx, 2));
            mx = fmaxf(mx, __shfl_xor(mx, 4));
            mx = fmaxf(mx, __shfl_xor(mx, 8));
            float mnew = fmaxf(mrow[r], mx);
            float al = __expf(mrow[r] - mnew);
            float ls = 0.f;
#pragma unroll
            for (int tt = 0; tt < 4; ++tt) {
                float p = (s[tt] <= -20000.f) ? 0.f : __expf(s[tt] - mnew);
                ls += p;
                Pbf[lrowq * 72 + 16 * tt + m] = (bf16)p;
            }
            ls += __shfl_xor(ls, 1);
            ls += __shfl_xor(ls, 2);
            ls += __shfl_xor(ls, 4);
            ls += __shfl_xor(ls, 8);
            lrow[r] = lrow[r] * al + ls;
            mrow[r] = mnew;
            alpha[r] = al;
        }
#pragma unroll
        for (int tt = 0; tt < 4; ++tt)
#pragma unroll
            for (int r = 0; r < 4; ++r) ctx[tt][r] *= alpha[r];

        // PV (Pbf rows 16w..16w+15 wave-private; VsT stable since stage sync)
#pragma unroll
        for (int st = 0; st < 2; ++st) {
            bf16x8 pf = *(const bf16x8*)&Pbf[(16 * w + m) * 72 + 8 * quad + 32 * st];
#pragma unroll
            for (int tt = 0; tt < 4; ++tt) {
                bf16x8 vf = *(const bf16x8*)&VsT[(16 * tt + m) * 72 + 8 * quad + 32 * st];
                ctx[tt] = __builtin_amdgcn_mfma_f32_16x16x32_bf16(pf, vf, ctx[tt], 0, 0, 0);
            }
        }
    }

    // epilogue: normalized ctx, pre-split hi/lo bf16 for out-GEMM
#pragma unroll
    for (int r = 0; r < 4; ++r) {
        float inv = lrow[r] > 0.f ? 1.f / lrow[r] : 0.f;
        int grow = q0 + 16 * w + 4 * quad + r;
#pragma unroll
        for (int tt = 0; tt < 4; ++tt) {
            float v = ctx[tt][r] * inv;
            bf16 hv = (bf16)v;
            size_t o = ((size_t)b * S_LEN + grow) * CH + h * HD + 16 * tt + m;
            ctxhi[o] = hv;
            ctxlo[o] = (bf16)(v - (float)hv);
        }
    }
}

extern "C" void kernel_launch(void* const* d_in, const int* in_sizes, int n_in,
                              void* d_out, int out_size, void* d_ws, size_t ws_size,
                              hipStream_t stream) {
    const float* k_in = (const float*)d_in[0];
    const float* v_in = (const float*)d_in[1];
    const float* q_in = (const float*)d_in[2];
    const void*  mask = d_in[3];
    const float* bias = (const float*)d_in[4];
    const float* Wq = (const float*)d_in[5];
    const float* bq = (const float*)d_in[6];
    const float* Wk = (const float*)d_in[7];
    const float* bk = (const float*)d_in[8];
    const float* Wv = (const float*)d_in[9];
    const float* bv = (const float*)d_in[10];
    const float* Wo = (const float*)d_in[11];
    const float* bo = (const float*)d_in[12];
    float* out = (float*)d_out;

    float* wsf = (float*)d_ws;
    bf16*  qp    = (bf16*)wsf;                 // [B,H,S,D] bf16  4 MB
    bf16*  kp    = (bf16*)(wsf + 1048576);     // 4 MB
    bf16*  vpT   = (bf16*)(wsf + 2097152);     // [B,H,D,S] bf16  4 MB
    bf16*  ctxhi = (bf16*)(wsf + 3145728);     // [B,S,CH] bf16   4 MB
    bf16*  ctxlo = (bf16*)(wsf + 4194304);     // 4 MB
    bf16*  WThi  = (bf16*)(wsf + 5242880);     // 4 mats x 512^2  2 MB
    bf16*  WTlo  = (bf16*)(wsf + 5767168);     // 2 MB
    int*   flag  = (int*)(wsf + 6291456);
    f16*   sbias = (f16*)(wsf + 8388608);      // [NH,S,S] f16   64 MB (ends at 96 MB)

    detect_mask_kernel<<<1, 256, 0, stream>>>((const unsigned char*)mask, flag);
    prep_weights_kernel<<<dim3(8, 8, 4), 256, 0, stream>>>(
        Wq, Wk, Wv, Wo, WThi, WTlo);
    prep_sbias_kernel<<<4096, 256, 0, stream>>>(bias, mask, flag, sbias);
    qkv_gemm_kernel<<<dim3(4, 32, 3), 256, 0, stream>>>(
        q_in, k_in, v_in, WThi, WTlo, bq, bk, bv, qp, kp, vpT);
    attn_kernel<<<dim3(32, 8, 2), 256, 0, stream>>>(
        qp, kp, vpT, sbias, ctxhi, ctxlo);
    out_gemm_kernel<<<dim3(4, 32), 256, 0, stream>>>(
        ctxhi, ctxlo, WThi, WTlo, bo, out);
}